// Round 14
// baseline (225.336 us; speedup 1.0000x reference)
//
#include <hip/hip_runtime.h>
#include <hip/hip_bf16.h>
#include <math.h>
#include <stdint.h>

typedef unsigned short u16;
typedef __attribute__((ext_vector_type(8))) short bf8;    // 8 bf16 raw bits (4 VGPRs)
typedef __attribute__((ext_vector_type(4))) float f4;     // 16x16 MFMA C/D frag

#define SC_LOG2E 0.09016844f   // 256^-0.5 * log2(e)

__device__ __forceinline__ float b2f(u16 u) {
    union { uint32_t i; float f; } v; v.i = ((uint32_t)u) << 16; return v.f;
}
__device__ __forceinline__ u16 f2b(float f) {
    union { float f; uint32_t i; } v; v.f = f;
    uint32_t r = (v.i + 0x7FFFu + ((v.i >> 16) & 1u)) >> 16;
    return (u16)r;
}
// pack two f32 -> two bf16 in one dword (RNE), 1 VALU op
__device__ __forceinline__ uint32_t pk_bf16(float lo, float hi) {
    uint32_t r;
    asm("v_cvt_pk_bf16_f32 %0, %1, %2" : "=v"(r) : "v"(lo), "v"(hi));
    return r;
}

// ---------------------------------------------------------------------------
// Kernel 0: weight prep (transpose via LDS tile, coalesced both sides) +
// x cast, one launch.
// ---------------------------------------------------------------------------
__global__ __launch_bounds__(256) void prep_all(
        const float* __restrict__ Wqkv, const float* __restrict__ Wgate,
        const float* __restrict__ Wproj, const float* __restrict__ x,
        u16* __restrict__ WT_all, u16* __restrict__ WTp,
        u16* __restrict__ xb) {
    int bid = blockIdx.x;
    if (bid < 80) {
        __shared__ float tile[64][65];
        int t = threadIdx.x;
        int lid = (bid < 64) ? bid : (bid - 64);
        int n0 = (lid >> 2) * 64, k0 = (lid & 3) * 64;
        const float* src; int stride, ncol; u16* dst;
        if (bid < 64) {
            if (n0 < 768) { src = Wqkv; stride = 768; ncol = n0; }
            else          { src = Wgate; stride = 256; ncol = n0 - 768; }
            dst = WT_all;
        } else { src = Wproj; stride = 256; ncol = n0; dst = WTp; }
        int cr = t & 63, rr = t >> 6;
#pragma unroll
        for (int i = 0; i < 16; i++) {
            int r = rr * 16 + i;
            tile[r][cr] = src[(size_t)(k0 + r) * stride + ncol + cr];
        }
        __syncthreads();
#pragma unroll
        for (int i = 0; i < 16; i++) {
            int rw = rr * 16 + i;
            dst[(size_t)(n0 + rw) * 256 + k0 + cr] = f2b(tile[cr][rw]);
        }
    } else {
        int i = ((bid - 80) * 256 + threadIdx.x) * 4;
        float4 f = *(const float4*)&x[i];
        uint2 o;
        o.x = pk_bf16(f.x, f.y);
        o.y = pk_bf16(f.z, f.w);
        *(uint2*)&xb[i] = o;
    }
}

// ---------------------------------------------------------------------------
// Kernel 1: fused GEMM  y = xb @ [W_qkv | W_gate]  (M=16384, N=1024, K=256)
// v20: persistent-A + 16 B-panels (32 n-rows) with 3-buffer counted-vmcnt
// pipeline (T4, textbook uniform loop): panel p+2 DMA issued 2 panels
// ahead; per-panel sync = s_waitcnt vmcnt(2) (retire oldest panel, newest
// stays in flight) + raw s_barrier. No vmcnt(0) drain in the loop — each
// panel's DMA gets 2 panel-computes of span instead of <1.
// Race-free: stageB(p+2) targets buffer (p-1)%3, whose reads all waves
// finished before the barrier it is issued after; panel-p visibility =
// per-wave vmcnt(2) precondition + barrier.
// ---------------------------------------------------------------------------
__global__ __launch_bounds__(512) void gemm_qkvz(
        const u16* __restrict__ xb, const u16* __restrict__ WT,
        const float* __restrict__ b_gate,
        u16* __restrict__ qo, u16* __restrict__ ko,
        u16* __restrict__ vT, u16* __restrict__ zo) {
    __shared__ u16 As[64 * 520];       // 128 rows x 256 k, pair-1040B, swz
    __shared__ u16 Bp[3][16 * 520];    // 3 x (32 rows x 256 k)
    const int t = threadIdx.x;
    const int w = t >> 6, lane = t & 63, l15 = lane & 15, q4 = lane >> 4;
    const int m0 = blockIdx.x * 128;
    const int nb = blockIdx.y * 512;   // n-half base within WT (1024 rows)

    const int lo = lane >> 5;
    const int lcn = ((lane & 31) - 4 * lo) & 31;

    auto stageA = [&]() {
#pragma unroll
        for (int rr = 0; rr < 8; rr++) {
            int pp = rr * 8 + w;                 // pair 0..63
            const u16* g = &xb[(size_t)(m0 + pp * 2 + lo) * 256 + lcn * 8];
            __builtin_amdgcn_global_load_lds(
                (const __attribute__((address_space(1))) unsigned int*)g,
                (__attribute__((address_space(3))) unsigned int*)&As[pp * 520],
                16, 0, 0);
        }
    };
    auto stageB = [&](int p, u16* dst) {         // 32 rows = 16 pairs, 2 ops
#pragma unroll
        for (int rr = 0; rr < 2; rr++) {
            int pp = rr * 8 + w;                 // pair 0..15
            const u16* g = &WT[(size_t)(nb + p * 32 + pp * 2 + lo) * 256 + lcn * 8];
            __builtin_amdgcn_global_load_lds(
                (const __attribute__((address_space(1))) unsigned int*)g,
                (__attribute__((address_space(3))) unsigned int*)&dst[pp * 520],
                16, 0, 0);
        }
    };
    auto kaddr = [&](const u16* base, int row, int cn) -> const u16* {
        int o = row & 1;
        return base + (row >> 1) * 520 + o * 256 + (((cn + 4 * o) & 31) << 3);
    };

    stageA();
    stageB(0, Bp[0]);
    stageB(1, Bp[1]);
    __syncthreads();                   // A, p0, p1 resident (one-time drain)

    const int mtb = (w & 3) * 32;      // wave m-base (2 m-tiles of 16)
    const int ntb = (w >> 2) * 16;     // wave n-tile (2 wave-cols x 16)

    for (int p = 0; p < 16; ++p) {
        if (p > 0) {
            // in-flight: {p (2 ops, oldest), p+1 (2 ops)} -> retire p's only
            asm volatile("s_waitcnt vmcnt(2)" ::: "memory");
            __builtin_amdgcn_sched_barrier(0);
            __builtin_amdgcn_s_barrier();
            __builtin_amdgcn_sched_barrier(0);
        }
        if (p + 2 < 16) stageB(p + 2, Bp[(p + 2) % 3]);
        const u16* Bs = Bp[p % 3];
        const int n0g = nb + p * 32;
        const int kind = n0g >> 8;     // 0=q 1=k 2=vT 3=z
        const int pcol = n0g & 255;

        f4 acc[2];
        acc[0] = (f4){0.f, 0.f, 0.f, 0.f};
        acc[1] = (f4){0.f, 0.f, 0.f, 0.f};

        __builtin_amdgcn_s_setprio(1);
#pragma unroll
        for (int c = 0; c < 8; c++) {
            bf8 af0 = *(const bf8*)kaddr(As, mtb + l15, c * 4 + q4);
            bf8 af1 = *(const bf8*)kaddr(As, mtb + 16 + l15, c * 4 + q4);
            bf8 bf0 = *(const bf8*)kaddr(Bs, ntb + l15, c * 4 + q4);
            if (kind == 2) {           // vT: rows=m (unswapped)
                acc[0] = __builtin_amdgcn_mfma_f32_16x16x32_bf16(af0, bf0, acc[0], 0, 0, 0);
                acc[1] = __builtin_amdgcn_mfma_f32_16x16x32_bf16(af1, bf0, acc[1], 0, 0, 0);
            } else {                   // q/k/z: rows=n (swapped) -> packed col stores
                acc[0] = __builtin_amdgcn_mfma_f32_16x16x32_bf16(bf0, af0, acc[0], 0, 0, 0);
                acc[1] = __builtin_amdgcn_mfma_f32_16x16x32_bf16(bf0, af1, acc[1], 0, 0, 0);
            }
        }
        __builtin_amdgcn_s_setprio(0);

        if (kind == 2) {               // vT[b][c][n]: 4 consecutive m per lane
            int bb = m0 >> 12;
            int nnb = (m0 & 4095) + mtb + q4 * 4;
#pragma unroll
            for (int i = 0; i < 2; i++) {
                int nn = nnb + i * 16;
                int vc = pcol + ntb + l15;
                uint2 pk;
                pk.x = pk_bf16(acc[i][0], acc[i][1]);
                pk.y = pk_bf16(acc[i][2], acc[i][3]);
                *(uint2*)&vT[(size_t)(bb * 256 + vc) * 4096 + nn] = pk;
            }
        } else if (kind == 3) {        // z = gelu(y + bg)
#pragma unroll
            for (int i = 0; i < 2; i++) {
                size_t mrow = (size_t)(m0 + mtb + i * 16 + l15) * 256 + pcol;
                int col = ntb + q4 * 4;
                float4 bg4 = *(const float4*)&b_gate[pcol + col];
                float v0 = acc[i][0] + bg4.x;
                float v1 = acc[i][1] + bg4.y;
                float v2 = acc[i][2] + bg4.z;
                float v3 = acc[i][3] + bg4.w;
                v0 = 0.5f * v0 * (1.0f + erff(v0 * 0.70710678118654752f));
                v1 = 0.5f * v1 * (1.0f + erff(v1 * 0.70710678118654752f));
                v2 = 0.5f * v2 * (1.0f + erff(v2 * 0.70710678118654752f));
                v3 = 0.5f * v3 * (1.0f + erff(v3 * 0.70710678118654752f));
                uint2 o;
                o.x = pk_bf16(v0, v1);
                o.y = pk_bf16(v2, v3);
                *(uint2*)&zo[mrow + col] = o;
            }
        } else {                       // q/k
            u16* dst = (kind == 0) ? qo : ko;
#pragma unroll
            for (int i = 0; i < 2; i++) {
                size_t mrow = (size_t)(m0 + mtb + i * 16 + l15) * 256 + pcol;
                int col = ntb + q4 * 4;
                uint2 o;
                o.x = pk_bf16(acc[i][0], acc[i][1]);
                o.y = pk_bf16(acc[i][2], acc[i][3]);
                *(uint2*)&dst[mrow + col] = o;
            }
        }
    }
}

// ---------------------------------------------------------------------------
// Kernel 2: depthwise 3x3 conv PE, vectorized (4 ch/thread, ushort4 I/O).
// ---------------------------------------------------------------------------
__global__ __launch_bounds__(256) void conv_pe(
        const u16* __restrict__ q, const float* __restrict__ pw,
        const float* __restrict__ pb, u16* __restrict__ pe) {
    const int bid = blockIdx.x;
    const int b = bid >> 8, h = (bid >> 2) & 63, wsg = bid & 3;
    const int t = threadIdx.x;
    const int c4 = (t & 63) * 4;       // channel group (lane -> coalesced)
    const int ws4 = t >> 6;            // wave id -> w-subsegment
    const int w0 = wsg * 16 + ws4 * 4; // first of 4 output w-positions

    float wf[36];
#pragma unroll
    for (int j = 0; j < 9; j++) {
        float4 v = *(const float4*)&pw[c4 * 9 + j * 4];
        wf[j * 4 + 0] = v.x; wf[j * 4 + 1] = v.y;
        wf[j * 4 + 2] = v.z; wf[j * 4 + 3] = v.w;
    }
    float4 bias4 = *(const float4*)&pb[c4];
    float bias[4] = {bias4.x, bias4.y, bias4.z, bias4.w};

    const u16* qb = q + b * (4096 * 256);
    u16* peb = pe + b * (4096 * 256);
    const bool vTop = h > 0, vBot = h < 63;

    float v[3][6][4];
#pragma unroll
    for (int j = 0; j < 6; j++) {
        int pos = w0 - 1 + j;
        bool inw = (pos >= 0) && (pos < 64);
#pragma unroll
        for (int r = 0; r < 3; r++) {
            bool ok = inw && ((r == 0) ? vTop : (r == 2) ? vBot : true);
            ushort4 u4 = {0, 0, 0, 0};
            if (ok) u4 = *(const ushort4*)&qb[((h - 1 + r) * 64 + pos) * 256 + c4];
            v[r][j][0] = b2f(u4.x); v[r][j][1] = b2f(u4.y);
            v[r][j][2] = b2f(u4.z); v[r][j][3] = b2f(u4.w);
        }
    }
#pragma unroll
    for (int w2 = 0; w2 < 4; w2++) {
        float o[4];
#pragma unroll
        for (int ch = 0; ch < 4; ch++) {
            float acc = bias[ch];
#pragma unroll
            for (int r = 0; r < 3; r++)
#pragma unroll
                for (int j = 0; j < 3; j++)
                    acc += wf[ch * 9 + r * 3 + j] * v[r][w2 + j][ch];
            o[ch] = acc;
        }
        uint2 st;
        st.x = pk_bf16(o[0], o[1]);
        st.y = pk_bf16(o[2], o[3]);
        *(uint2*)&peb[(h * 64 + w0 + w2) * 256 + c4] = st;
    }
}

// ---------------------------------------------------------------------------
// Kernel 3: flash attention v19 (219.9us best) — UNCHANGED.
// ---------------------------------------------------------------------------
__global__ __launch_bounds__(512) void attn(
        const u16* __restrict__ q, const u16* __restrict__ k,
        const u16* __restrict__ vT, const u16* __restrict__ pe,
        const u16* __restrict__ z, const u16* __restrict__ WTp,
        float* __restrict__ out) {
    __shared__ u16 Kst[32 * 520];      // 64 rows x 256, pair-1040B, swizzled
    __shared__ u16 Vs2[2][256 * 64];   // [vc][64 keys], 128B rows, rotated
    __shared__ u16 Ps[64 * 72];        // [q][64 keys + 8 pad]
    __shared__ float l_part[8][64];

    const int t = threadIdx.x;
    const int w = t >> 6, lane = t & 63, l15 = lane & 15, q4 = lane >> 4;
    const int kg = w >> 1, qh = w & 1;
    const int xcd = blockIdx.x & 7;
    const int b = xcd >> 1;
    const int qt = (blockIdx.x >> 3) * 2 + (xcd & 1);
    const int m0 = b * 4096 + qt * 64;

    const u16* kb = k + (size_t)b * 4096 * 256;
    const u16* vbase = vT + (size_t)b * 256 * 4096;

    const int lo = lane >> 5;
    const int lcn = ((lane & 31) - 4 * lo) & 31;

    auto stage64 = [&](const u16* src) {
#pragma unroll
        for (int rr = 0; rr < 4; rr++) {
            int pp = rr * 8 + w;                 // pair index 0..31
            const u16* g = src + (size_t)(pp * 2 + lo) * 256 + lcn * 8;
            u16* l = &Kst[pp * 520];
            __builtin_amdgcn_global_load_lds(
                (const __attribute__((address_space(1))) unsigned int*)g,
                (__attribute__((address_space(3))) unsigned int*)l, 16, 0, 0);
        }
    };
    const int vrl = lane >> 3, vsl = lane & 7;
    auto stageV = [&](const u16* src, u16* dst) {  // src = vbase + kt*64
#pragma unroll
        for (int j = 0; j < 4; j++) {
            int op = j * 8 + w;                  // 0..31
            int r = op * 8 + vrl;
            int cn = (vsl - r) & 7;
            const u16* g = src + (size_t)r * 4096 + cn * 8;
            u16* l = dst + op * 512;
            __builtin_amdgcn_global_load_lds(
                (const __attribute__((address_space(1))) unsigned int*)g,
                (__attribute__((address_space(3))) unsigned int*)l, 16, 0, 0);
        }
    };
    auto kaddr = [&](int row, int cn) -> const u16* {
        int o = row & 1;
        return &Kst[(row >> 1) * 520 + o * 256 + (((cn + 4 * o) & 31) << 3)];
    };

    stage64(q + (size_t)m0 * 256);
    __syncthreads();
    bf8 qf[2][8];
#pragma unroll
    for (int qtt = 0; qtt < 2; qtt++)
#pragma unroll
        for (int c = 0; c < 8; c++)
            qf[qtt][c] = *(const bf8*)kaddr(qh * 32 + qtt * 16 + l15, c * 4 + q4);
    __syncthreads();                   // all qf reads done before K overwrites

    stage64(kb);                       // K[0]
    stageV(vbase, Vs2[0]);             // V[0]

    f4 O[2][4];
#pragma unroll
    for (int vg = 0; vg < 2; vg++)
#pragma unroll
        for (int qg = 0; qg < 4; qg++) O[vg][qg] = (f4){0.f, 0.f, 0.f, 0.f};
    float lrow[2] = {0.f, 0.f};

    auto body = [&](int kt, const u16* Vcur, u16* Vnxt) {
        __syncthreads();               // K[kt] in Kst, V[kt] in Vcur

        f4 St[2];
        St[0] = (f4){0.f, 0.f, 0.f, 0.f};
        St[1] = (f4){0.f, 0.f, 0.f, 0.f};
        __builtin_amdgcn_s_setprio(1);
#pragma unroll
        for (int c = 0; c < 8; c++) {
            bf8 kf = *(const bf8*)kaddr(kg * 16 + l15, c * 4 + q4);
            St[0] = __builtin_amdgcn_mfma_f32_16x16x32_bf16(kf, qf[0][c], St[0], 0, 0, 0);
            St[1] = __builtin_amdgcn_mfma_f32_16x16x32_bf16(kf, qf[1][c], St[1], 0, 0, 0);
        }
        __builtin_amdgcn_s_setprio(0);

#pragma unroll
        for (int qtt = 0; qtt < 2; qtt++) {
            float e0 = exp2f(St[qtt][0] * SC_LOG2E);
            float e1 = exp2f(St[qtt][1] * SC_LOG2E);
            float e2 = exp2f(St[qtt][2] * SC_LOG2E);
            float e3 = exp2f(St[qtt][3] * SC_LOG2E);
            uint2 pk;
            pk.x = pk_bf16(e0, e1);
            pk.y = pk_bf16(e2, e3);
            int qrow = qh * 32 + qtt * 16 + l15;
            *(uint2*)&Ps[qrow * 72 + kg * 16 + q4 * 4] = pk;
            lrow[qtt] += (e0 + e1) + (e2 + e3);   // per-lane partial; reduce after loop
        }
        __syncthreads();               // P visible; Kst kf reads done

        if (kt < 63) {
            stage64(kb + (size_t)(kt + 1) * 16384);
            stageV(vbase + (size_t)(kt + 1) * 64, Vnxt);
        }

        bf8 pf[4][2], vfr[2][2];
#pragma unroll
        for (int qg = 0; qg < 4; qg++)
#pragma unroll
            for (int kh = 0; kh < 2; kh++)
                pf[qg][kh] = *(bf8*)&Ps[(qg * 16 + l15) * 72 + kh * 32 + q4 * 8];
#pragma unroll
        for (int vg = 0; vg < 2; vg++)
#pragma unroll
            for (int kh = 0; kh < 2; kh++) {
                int R = w * 32 + vg * 16 + l15;
                int slot = ((kh * 4 + q4) + R) & 7;
                vfr[vg][kh] = *(const bf8*)&Vcur[R * 64 + slot * 8];
            }
        __builtin_amdgcn_s_setprio(1);
#pragma unroll
        for (int vg = 0; vg < 2; vg++)
#pragma unroll
            for (int qg = 0; qg < 4; qg++) {
                O[vg][qg] = __builtin_amdgcn_mfma_f32_16x16x32_bf16(
                    vfr[vg][0], pf[qg][0], O[vg][qg], 0, 0, 0);
                O[vg][qg] = __builtin_amdgcn_mfma_f32_16x16x32_bf16(
                    vfr[vg][1], pf[qg][1], O[vg][qg], 0, 0, 0);
            }
        __builtin_amdgcn_s_setprio(0);
    };

    for (int kt2 = 0; kt2 < 64; kt2 += 2) {
        body(kt2,     Vs2[0], Vs2[1]);
        body(kt2 + 1, Vs2[1], Vs2[0]);
    }

    // ---- deferred l-reduction: once instead of per-iter ----
#pragma unroll
    for (int qtt = 0; qtt < 2; qtt++) {
        float s = lrow[qtt];
        s += __shfl_xor(s, 16);
        s += __shfl_xor(s, 32);
        lrow[qtt] = s;
    }
    if (q4 == 0) {
        l_part[w][qh * 32 + l15] = lrow[0];
        l_part[w][qh * 32 + 16 + l15] = lrow[1];
    }
    __syncthreads();                   // loop LDS traffic fully retired

    // ---- epilogue: u = (O/l + pe) * z -> bf16 into Us (Kst space) ----
    u16* Us = Kst;
#pragma unroll
    for (int qg = 0; qg < 4; qg++) {
        int qrow = qg * 16 + l15;
        int qhq = qg >> 1;
        float lt = l_part[qhq][qrow] + l_part[2 + qhq][qrow]
                 + l_part[4 + qhq][qrow] + l_part[6 + qhq][qrow];
        float linv = 1.0f / lt;
        size_t mrow = (size_t)(m0 + qrow) * 256;
#pragma unroll
        for (int vg = 0; vg < 2; vg++) {
            int vcb = w * 32 + vg * 16 + q4 * 4;
            ushort4 pe4 = *(const ushort4*)&pe[mrow + vcb];
            ushort4 z4  = *(const ushort4*)&z[mrow + vcb];
            float r0 = (O[vg][qg][0] * linv + b2f(pe4.x)) * b2f(z4.x);
            float r1 = (O[vg][qg][1] * linv + b2f(pe4.y)) * b2f(z4.y);
            float r2 = (O[vg][qg][2] * linv + b2f(pe4.z)) * b2f(z4.z);
            float r3 = (O[vg][qg][3] * linv + b2f(pe4.w)) * b2f(z4.w);
            uint2 o4;
            o4.x = pk_bf16(r0, r1);
            o4.y = pk_bf16(r2, r3);
            int cn = vcb >> 3;
            int slot = (cn + qrow) & 31;
            *(uint2*)&Us[qrow * 256 + slot * 8 + (vcb & 7)] = o4;
        }
    }

    // ---- fused proj: out_block = Us @ Wproj, 4 quarter-passes ----
    auto stageW = [&](const u16* src, u16* dst) {
#pragma unroll
        for (int j = 0; j < 4; j++) {
            int op = j * 8 + w;                  // 0..31
            int r = op * 2 + lo;                 // local n-row 0..63
            int cn = ((lane & 31) - r) & 31;
            const u16* g = src + (size_t)r * 256 + cn * 8;
            __builtin_amdgcn_global_load_lds(
                (const __attribute__((address_space(1))) unsigned int*)g,
                (__attribute__((address_space(3))) unsigned int*)&dst[op * 512],
                16, 0, 0);
        }
    };

    stageW(WTp, (u16*)Vs2[0]);
    __syncthreads();                   // Us visible + WTp quarter 0 resident

    const int mtl = (w & 3) * 16;      // wave m-tile (local row base)
    const int ntl = (w >> 2) * 32;     // wave n-base within quarter
#pragma unroll
    for (int nq = 0; nq < 4; nq++) {
        if (nq < 3) stageW(WTp + (size_t)(nq + 1) * 64 * 256, (u16*)Vs2[(nq + 1) & 1]);
        const u16* Wl = (const u16*)Vs2[nq & 1];
        f4 a0 = (f4){0.f, 0.f, 0.f, 0.f};
        f4 a1 = (f4){0.f, 0.f, 0.f, 0.f};
        const int mrowL = mtl + l15;
        const int ln0 = ntl + l15, ln1 = ntl + 16 + l15;
        __builtin_amdgcn_s_setprio(1);
#pragma unroll
        for (int c = 0; c < 8; c++) {
            int cc = c * 4 + q4;
            bf8 af = *(const bf8*)&Us[mrowL * 256 + (((cc + mrowL) & 31) << 3)];
            bf8 b0 = *(const bf8*)&Wl[ln0 * 256 + (((cc + ln0) & 31) << 3)];
            bf8 b1 = *(const bf8*)&Wl[ln1 * 256 + (((cc + ln1) & 31) << 3)];
            a0 = __builtin_amdgcn_mfma_f32_16x16x32_bf16(b0, af, a0, 0, 0, 0);
            a1 = __builtin_amdgcn_mfma_f32_16x16x32_bf16(b1, af, a1, 0, 0, 0);
        }
        __builtin_amdgcn_s_setprio(0);
        float* ob = &out[(size_t)(m0 + mrowL) * 256 + nq * 64 + ntl];
        *(f4*)&ob[q4 * 4] = a0;
        *(f4*)&ob[16 + q4 * 4] = a1;
        __syncthreads();               // Wl reads done before its restage;
                                       // next quarter's DMA drained
    }
}

// ---------------------------------------------------------------------------
extern "C" void kernel_launch(void* const* d_in, const int* in_sizes, int n_in,
                              void* d_out, int out_size, void* d_ws, size_t ws_size,
                              hipStream_t stream) {
    (void)in_sizes; (void)n_in; (void)out_size; (void)ws_size;
    const float* x      = (const float*)d_in[0];
    const float* Wqkv   = (const float*)d_in[1];
    const float* Wgate  = (const float*)d_in[2];
    const float* bgate  = (const float*)d_in[3];
    const float* Wproj  = (const float*)d_in[4];
    const float* pw     = (const float*)d_in[5];
    const float* pb     = (const float*)d_in[6];
    float* out = (float*)d_out;

    char* ws = (char*)d_ws;
    u16* WT_all = (u16*)(ws);                   // 524288 B
    u16* WTp    = (u16*)(ws + 524288);          // 131072 B
    u16* q      = (u16*)(ws + 655360);          // 8388608
    u16* k      = (u16*)(ws + 9043968);         // 8388608
    u16* vT     = (u16*)(ws + 17432576);        // 8388608
    u16* z      = (u16*)(ws + 25821184);        // 8388608
    u16* pe     = (u16*)(ws + 34209792);        // 8388608
    u16* xb     = (u16*)(ws + 42598400);        // 8388608 (x as bf16)

    prep_all<<<4176, 256, 0, stream>>>(Wqkv, Wgate, Wproj, x, WT_all, WTp, xb);
    gemm_qkvz<<<dim3(128, 2), 512, 0, stream>>>(xb, WT_all, bgate, q, k, vT, z);
    conv_pe<<<1024, 256, 0, stream>>>(q, pw, pb, pe);
    attn<<<256, 512, 0, stream>>>(q, k, vT, pe, z, WTp, out);
}

// Round 16
// 220.950 us; speedup vs baseline: 1.0198x; 1.0198x over previous
//
#include <hip/hip_runtime.h>
#include <hip/hip_bf16.h>
#include <math.h>
#include <stdint.h>

typedef unsigned short u16;
typedef __attribute__((ext_vector_type(8))) short bf8;    // 8 bf16 raw bits (4 VGPRs)
typedef __attribute__((ext_vector_type(4))) float f4;     // 16x16 MFMA C/D frag

#define SC_LOG2E 0.09016844f   // 256^-0.5 * log2(e)

__device__ __forceinline__ float b2f(u16 u) {
    union { uint32_t i; float f; } v; v.i = ((uint32_t)u) << 16; return v.f;
}
__device__ __forceinline__ u16 f2b(float f) {
    union { float f; uint32_t i; } v; v.f = f;
    uint32_t r = (v.i + 0x7FFFu + ((v.i >> 16) & 1u)) >> 16;
    return (u16)r;
}
// pack two f32 -> two bf16 in one dword (RNE), 1 VALU op
__device__ __forceinline__ uint32_t pk_bf16(float lo, float hi) {
    uint32_t r;
    asm("v_cvt_pk_bf16_f32 %0, %1, %2" : "=v"(r) : "v"(lo), "v"(hi));
    return r;
}

// ---------------------------------------------------------------------------
// Kernel 0: weight prep (transpose via LDS tile, coalesced both sides) +
// x cast, one launch.
// ---------------------------------------------------------------------------
__global__ __launch_bounds__(256) void prep_all(
        const float* __restrict__ Wqkv, const float* __restrict__ Wgate,
        const float* __restrict__ Wproj, const float* __restrict__ x,
        u16* __restrict__ WT_all, u16* __restrict__ WTp,
        u16* __restrict__ xb) {
    int bid = blockIdx.x;
    if (bid < 80) {
        __shared__ float tile[64][65];
        int t = threadIdx.x;
        int lid = (bid < 64) ? bid : (bid - 64);
        int n0 = (lid >> 2) * 64, k0 = (lid & 3) * 64;
        const float* src; int stride, ncol; u16* dst;
        if (bid < 64) {
            if (n0 < 768) { src = Wqkv; stride = 768; ncol = n0; }
            else          { src = Wgate; stride = 256; ncol = n0 - 768; }
            dst = WT_all;
        } else { src = Wproj; stride = 256; ncol = n0; dst = WTp; }
        int cr = t & 63, rr = t >> 6;
#pragma unroll
        for (int i = 0; i < 16; i++) {
            int r = rr * 16 + i;
            tile[r][cr] = src[(size_t)(k0 + r) * stride + ncol + cr];
        }
        __syncthreads();
#pragma unroll
        for (int i = 0; i < 16; i++) {
            int rw = rr * 16 + i;
            dst[(size_t)(n0 + rw) * 256 + k0 + cr] = f2b(tile[cr][rw]);
        }
    } else {
        int i = ((bid - 80) * 256 + threadIdx.x) * 4;
        float4 f = *(const float4*)&x[i];
        uint2 o;
        o.x = pk_bf16(f.x, f.y);
        o.y = pk_bf16(f.z, f.w);
        *(uint2*)&xb[i] = o;
    }
}

// ---------------------------------------------------------------------------
// Kernel 1: fused GEMM  y = xb @ [W_qkv | W_gate]  (v17 persistent-A form;
// v20's thinner counted-vmcnt panels REGRESSED and are reverted).
// ---------------------------------------------------------------------------
__global__ __launch_bounds__(512) void gemm_qkvz(
        const u16* __restrict__ xb, const u16* __restrict__ WT,
        const float* __restrict__ b_gate,
        u16* __restrict__ qo, u16* __restrict__ ko,
        u16* __restrict__ vT, u16* __restrict__ zo) {
    __shared__ u16 As[64 * 520];       // 128 rows x 256 k, pair-1040B, swz
    __shared__ u16 Bp[2][32 * 520];    // 2 x (64 rows x 256 k)
    const int t = threadIdx.x;
    const int w = t >> 6, lane = t & 63, l15 = lane & 15, q4 = lane >> 4;
    const int m0 = blockIdx.x * 128;
    const int nb = blockIdx.y * 512;   // n-half base within WT (1024 rows)

    const int lo = lane >> 5;
    const int lcn = ((lane & 31) - 4 * lo) & 31;

    auto stageA = [&]() {
#pragma unroll
        for (int rr = 0; rr < 8; rr++) {
            int pp = rr * 8 + w;                 // pair 0..63
            const u16* g = &xb[(size_t)(m0 + pp * 2 + lo) * 256 + lcn * 8];
            __builtin_amdgcn_global_load_lds(
                (const __attribute__((address_space(1))) unsigned int*)g,
                (__attribute__((address_space(3))) unsigned int*)&As[pp * 520],
                16, 0, 0);
        }
    };
    auto stageB = [&](int p, u16* dst) {
#pragma unroll
        for (int rr = 0; rr < 4; rr++) {
            int pp = rr * 8 + w;                 // pair 0..31
            const u16* g = &WT[(size_t)(nb + p * 64 + pp * 2 + lo) * 256 + lcn * 8];
            __builtin_amdgcn_global_load_lds(
                (const __attribute__((address_space(1))) unsigned int*)g,
                (__attribute__((address_space(3))) unsigned int*)&dst[pp * 520],
                16, 0, 0);
        }
    };
    auto kaddr = [&](const u16* base, int row, int cn) -> const u16* {
        int o = row & 1;
        return base + (row >> 1) * 520 + o * 256 + (((cn + 4 * o) & 31) << 3);
    };

    stageA();
    stageB(0, Bp[0]);

    const int mtb = (w & 3) * 32;      // wave m-base (2 m-tiles of 16)
    const int ntb = (w >> 2) * 32;     // wave n-base (2 n-tiles of 16)

    for (int p = 0; p < 8; ++p) {
        __syncthreads();               // A + B[p] DMA drained; B[p+1&1] reads retired
        if (p < 7) stageB(p + 1, Bp[(p + 1) & 1]);
        const u16* Bs = Bp[p & 1];
        const int n0g = nb + p * 64;
        const int kind = n0g >> 8;     // 0=q 1=k 2=vT 3=z
        const int pcol = n0g & 255;

        f4 acc[2][2];
#pragma unroll
        for (int i = 0; i < 2; i++)
#pragma unroll
            for (int j = 0; j < 2; j++) acc[i][j] = (f4){0.f, 0.f, 0.f, 0.f};

        __builtin_amdgcn_s_setprio(1);
#pragma unroll
        for (int c = 0; c < 8; c++) {
            bf8 af0 = *(const bf8*)kaddr(As, mtb + l15, c * 4 + q4);
            bf8 af1 = *(const bf8*)kaddr(As, mtb + 16 + l15, c * 4 + q4);
            bf8 bf0 = *(const bf8*)kaddr(Bs, ntb + l15, c * 4 + q4);
            bf8 bf1 = *(const bf8*)kaddr(Bs, ntb + 16 + l15, c * 4 + q4);
            if (kind == 2) {           // vT: rows=m (unswapped)
                acc[0][0] = __builtin_amdgcn_mfma_f32_16x16x32_bf16(af0, bf0, acc[0][0], 0, 0, 0);
                acc[0][1] = __builtin_amdgcn_mfma_f32_16x16x32_bf16(af0, bf1, acc[0][1], 0, 0, 0);
                acc[1][0] = __builtin_amdgcn_mfma_f32_16x16x32_bf16(af1, bf0, acc[1][0], 0, 0, 0);
                acc[1][1] = __builtin_amdgcn_mfma_f32_16x16x32_bf16(af1, bf1, acc[1][1], 0, 0, 0);
            } else {                   // q/k/z: rows=n (swapped) -> packed col stores
                acc[0][0] = __builtin_amdgcn_mfma_f32_16x16x32_bf16(bf0, af0, acc[0][0], 0, 0, 0);
                acc[0][1] = __builtin_amdgcn_mfma_f32_16x16x32_bf16(bf1, af0, acc[0][1], 0, 0, 0);
                acc[1][0] = __builtin_amdgcn_mfma_f32_16x16x32_bf16(bf0, af1, acc[1][0], 0, 0, 0);
                acc[1][1] = __builtin_amdgcn_mfma_f32_16x16x32_bf16(bf1, af1, acc[1][1], 0, 0, 0);
            }
        }
        __builtin_amdgcn_s_setprio(0);

        if (kind == 2) {               // vT[b][c][n]: 4 consecutive m per lane
            int bb = m0 >> 12;
            int nnb = (m0 & 4095) + mtb + q4 * 4;
#pragma unroll
            for (int i = 0; i < 2; i++) {
                int nn = nnb + i * 16;
#pragma unroll
                for (int j = 0; j < 2; j++) {
                    int vc = pcol + ntb + j * 16 + l15;
                    uint2 pk;
                    pk.x = pk_bf16(acc[i][j][0], acc[i][j][1]);
                    pk.y = pk_bf16(acc[i][j][2], acc[i][j][3]);
                    *(uint2*)&vT[(size_t)(bb * 256 + vc) * 4096 + nn] = pk;
                }
            }
        } else if (kind == 3) {        // z = gelu(y + bg)
#pragma unroll
            for (int i = 0; i < 2; i++) {
                size_t mrow = (size_t)(m0 + mtb + i * 16 + l15) * 256 + pcol;
#pragma unroll
                for (int j = 0; j < 2; j++) {
                    int col = ntb + j * 16 + q4 * 4;
                    float4 bg4 = *(const float4*)&b_gate[pcol + col];
                    float v0 = acc[i][j][0] + bg4.x;
                    float v1 = acc[i][j][1] + bg4.y;
                    float v2 = acc[i][j][2] + bg4.z;
                    float v3 = acc[i][j][3] + bg4.w;
                    v0 = 0.5f * v0 * (1.0f + erff(v0 * 0.70710678118654752f));
                    v1 = 0.5f * v1 * (1.0f + erff(v1 * 0.70710678118654752f));
                    v2 = 0.5f * v2 * (1.0f + erff(v2 * 0.70710678118654752f));
                    v3 = 0.5f * v3 * (1.0f + erff(v3 * 0.70710678118654752f));
                    uint2 o;
                    o.x = pk_bf16(v0, v1);
                    o.y = pk_bf16(v2, v3);
                    *(uint2*)&zo[mrow + col] = o;
                }
            }
        } else {                       // q/k
            u16* dst = (kind == 0) ? qo : ko;
#pragma unroll
            for (int i = 0; i < 2; i++) {
                size_t mrow = (size_t)(m0 + mtb + i * 16 + l15) * 256 + pcol;
#pragma unroll
                for (int j = 0; j < 2; j++) {
                    int col = ntb + j * 16 + q4 * 4;
                    uint2 o;
                    o.x = pk_bf16(acc[i][j][0], acc[i][j][1]);
                    o.y = pk_bf16(acc[i][j][2], acc[i][j][3]);
                    *(uint2*)&dst[mrow + col] = o;
                }
            }
        }
    }
}

// ---------------------------------------------------------------------------
// Kernel 2: depthwise 3x3 conv PE, vectorized (4 ch/thread, ushort4 I/O).
// ---------------------------------------------------------------------------
__global__ __launch_bounds__(256) void conv_pe(
        const u16* __restrict__ q, const float* __restrict__ pw,
        const float* __restrict__ pb, u16* __restrict__ pe) {
    const int bid = blockIdx.x;
    const int b = bid >> 8, h = (bid >> 2) & 63, wsg = bid & 3;
    const int t = threadIdx.x;
    const int c4 = (t & 63) * 4;       // channel group (lane -> coalesced)
    const int ws4 = t >> 6;            // wave id -> w-subsegment
    const int w0 = wsg * 16 + ws4 * 4; // first of 4 output w-positions

    float wf[36];
#pragma unroll
    for (int j = 0; j < 9; j++) {
        float4 v = *(const float4*)&pw[c4 * 9 + j * 4];
        wf[j * 4 + 0] = v.x; wf[j * 4 + 1] = v.y;
        wf[j * 4 + 2] = v.z; wf[j * 4 + 3] = v.w;
    }
    float4 bias4 = *(const float4*)&pb[c4];
    float bias[4] = {bias4.x, bias4.y, bias4.z, bias4.w};

    const u16* qb = q + b * (4096 * 256);
    u16* peb = pe + b * (4096 * 256);
    const bool vTop = h > 0, vBot = h < 63;

    float v[3][6][4];
#pragma unroll
    for (int j = 0; j < 6; j++) {
        int pos = w0 - 1 + j;
        bool inw = (pos >= 0) && (pos < 64);
#pragma unroll
        for (int r = 0; r < 3; r++) {
            bool ok = inw && ((r == 0) ? vTop : (r == 2) ? vBot : true);
            ushort4 u4 = {0, 0, 0, 0};
            if (ok) u4 = *(const ushort4*)&qb[((h - 1 + r) * 64 + pos) * 256 + c4];
            v[r][j][0] = b2f(u4.x); v[r][j][1] = b2f(u4.y);
            v[r][j][2] = b2f(u4.z); v[r][j][3] = b2f(u4.w);
        }
    }
#pragma unroll
    for (int w2 = 0; w2 < 4; w2++) {
        float o[4];
#pragma unroll
        for (int ch = 0; ch < 4; ch++) {
            float acc = bias[ch];
#pragma unroll
            for (int r = 0; r < 3; r++)
#pragma unroll
                for (int j = 0; j < 3; j++)
                    acc += wf[ch * 9 + r * 3 + j] * v[r][w2 + j][ch];
            o[ch] = acc;
        }
        uint2 st;
        st.x = pk_bf16(o[0], o[1]);
        st.y = pk_bf16(o[2], o[3]);
        *(uint2*)&peb[(h * 64 + w0 + w2) * 256 + c4] = st;
    }
}

// ---------------------------------------------------------------------------
// Kernel 3: flash attention v19 (219.9us best) — UNCHANGED.
// ---------------------------------------------------------------------------
__global__ __launch_bounds__(512) void attn(
        const u16* __restrict__ q, const u16* __restrict__ k,
        const u16* __restrict__ vT, const u16* __restrict__ pe,
        const u16* __restrict__ z, const u16* __restrict__ WTp,
        float* __restrict__ out) {
    __shared__ u16 Kst[32 * 520];      // 64 rows x 256, pair-1040B, swizzled
    __shared__ u16 Vs2[2][256 * 64];   // [vc][64 keys], 128B rows, rotated
    __shared__ u16 Ps[64 * 72];        // [q][64 keys + 8 pad]
    __shared__ float l_part[8][64];

    const int t = threadIdx.x;
    const int w = t >> 6, lane = t & 63, l15 = lane & 15, q4 = lane >> 4;
    const int kg = w >> 1, qh = w & 1;
    const int xcd = blockIdx.x & 7;
    const int b = xcd >> 1;
    const int qt = (blockIdx.x >> 3) * 2 + (xcd & 1);
    const int m0 = b * 4096 + qt * 64;

    const u16* kb = k + (size_t)b * 4096 * 256;
    const u16* vbase = vT + (size_t)b * 256 * 4096;

    const int lo = lane >> 5;
    const int lcn = ((lane & 31) - 4 * lo) & 31;

    auto stage64 = [&](const u16* src) {
#pragma unroll
        for (int rr = 0; rr < 4; rr++) {
            int pp = rr * 8 + w;                 // pair index 0..31
            const u16* g = src + (size_t)(pp * 2 + lo) * 256 + lcn * 8;
            u16* l = &Kst[pp * 520];
            __builtin_amdgcn_global_load_lds(
                (const __attribute__((address_space(1))) unsigned int*)g,
                (__attribute__((address_space(3))) unsigned int*)l, 16, 0, 0);
        }
    };
    const int vrl = lane >> 3, vsl = lane & 7;
    auto stageV = [&](const u16* src, u16* dst) {  // src = vbase + kt*64
#pragma unroll
        for (int j = 0; j < 4; j++) {
            int op = j * 8 + w;                  // 0..31
            int r = op * 8 + vrl;
            int cn = (vsl - r) & 7;
            const u16* g = src + (size_t)r * 4096 + cn * 8;
            u16* l = dst + op * 512;
            __builtin_amdgcn_global_load_lds(
                (const __attribute__((address_space(1))) unsigned int*)g,
                (__attribute__((address_space(3))) unsigned int*)l, 16, 0, 0);
        }
    };
    auto kaddr = [&](int row, int cn) -> const u16* {
        int o = row & 1;
        return &Kst[(row >> 1) * 520 + o * 256 + (((cn + 4 * o) & 31) << 3)];
    };

    stage64(q + (size_t)m0 * 256);
    __syncthreads();
    bf8 qf[2][8];
#pragma unroll
    for (int qtt = 0; qtt < 2; qtt++)
#pragma unroll
        for (int c = 0; c < 8; c++)
            qf[qtt][c] = *(const bf8*)kaddr(qh * 32 + qtt * 16 + l15, c * 4 + q4);
    __syncthreads();                   // all qf reads done before K overwrites

    stage64(kb);                       // K[0]
    stageV(vbase, Vs2[0]);             // V[0]

    f4 O[2][4];
#pragma unroll
    for (int vg = 0; vg < 2; vg++)
#pragma unroll
        for (int qg = 0; qg < 4; qg++) O[vg][qg] = (f4){0.f, 0.f, 0.f, 0.f};
    float lrow[2] = {0.f, 0.f};

    auto body = [&](int kt, const u16* Vcur, u16* Vnxt) {
        __syncthreads();               // K[kt] in Kst, V[kt] in Vcur

        f4 St[2];
        St[0] = (f4){0.f, 0.f, 0.f, 0.f};
        St[1] = (f4){0.f, 0.f, 0.f, 0.f};
        __builtin_amdgcn_s_setprio(1);
#pragma unroll
        for (int c = 0; c < 8; c++) {
            bf8 kf = *(const bf8*)kaddr(kg * 16 + l15, c * 4 + q4);
            St[0] = __builtin_amdgcn_mfma_f32_16x16x32_bf16(kf, qf[0][c], St[0], 0, 0, 0);
            St[1] = __builtin_amdgcn_mfma_f32_16x16x32_bf16(kf, qf[1][c], St[1], 0, 0, 0);
        }
        __builtin_amdgcn_s_setprio(0);

#pragma unroll
        for (int qtt = 0; qtt < 2; qtt++) {
            float e0 = exp2f(St[qtt][0] * SC_LOG2E);
            float e1 = exp2f(St[qtt][1] * SC_LOG2E);
            float e2 = exp2f(St[qtt][2] * SC_LOG2E);
            float e3 = exp2f(St[qtt][3] * SC_LOG2E);
            uint2 pk;
            pk.x = pk_bf16(e0, e1);
            pk.y = pk_bf16(e2, e3);
            int qrow = qh * 32 + qtt * 16 + l15;
            *(uint2*)&Ps[qrow * 72 + kg * 16 + q4 * 4] = pk;
            lrow[qtt] += (e0 + e1) + (e2 + e3);   // per-lane partial; reduce after loop
        }
        __syncthreads();               // P visible; Kst kf reads done

        if (kt < 63) {
            stage64(kb + (size_t)(kt + 1) * 16384);
            stageV(vbase + (size_t)(kt + 1) * 64, Vnxt);
        }

        bf8 pf[4][2], vfr[2][2];
#pragma unroll
        for (int qg = 0; qg < 4; qg++)
#pragma unroll
            for (int kh = 0; kh < 2; kh++)
                pf[qg][kh] = *(bf8*)&Ps[(qg * 16 + l15) * 72 + kh * 32 + q4 * 8];
#pragma unroll
        for (int vg = 0; vg < 2; vg++)
#pragma unroll
            for (int kh = 0; kh < 2; kh++) {
                int R = w * 32 + vg * 16 + l15;
                int slot = ((kh * 4 + q4) + R) & 7;
                vfr[vg][kh] = *(const bf8*)&Vcur[R * 64 + slot * 8];
            }
        __builtin_amdgcn_s_setprio(1);
#pragma unroll
        for (int vg = 0; vg < 2; vg++)
#pragma unroll
            for (int qg = 0; qg < 4; qg++) {
                O[vg][qg] = __builtin_amdgcn_mfma_f32_16x16x32_bf16(
                    vfr[vg][0], pf[qg][0], O[vg][qg], 0, 0, 0);
                O[vg][qg] = __builtin_amdgcn_mfma_f32_16x16x32_bf16(
                    vfr[vg][1], pf[qg][1], O[vg][qg], 0, 0, 0);
            }
        __builtin_amdgcn_s_setprio(0);
    };

    for (int kt2 = 0; kt2 < 64; kt2 += 2) {
        body(kt2,     Vs2[0], Vs2[1]);
        body(kt2 + 1, Vs2[1], Vs2[0]);
    }

    // ---- deferred l-reduction: once instead of per-iter ----
#pragma unroll
    for (int qtt = 0; qtt < 2; qtt++) {
        float s = lrow[qtt];
        s += __shfl_xor(s, 16);
        s += __shfl_xor(s, 32);
        lrow[qtt] = s;
    }
    if (q4 == 0) {
        l_part[w][qh * 32 + l15] = lrow[0];
        l_part[w][qh * 32 + 16 + l15] = lrow[1];
    }
    __syncthreads();                   // loop LDS traffic fully retired

    // ---- epilogue: u = (O/l + pe) * z -> bf16 into Us (Kst space) ----
    u16* Us = Kst;
#pragma unroll
    for (int qg = 0; qg < 4; qg++) {
        int qrow = qg * 16 + l15;
        int qhq = qg >> 1;
        float lt = l_part[qhq][qrow] + l_part[2 + qhq][qrow]
                 + l_part[4 + qhq][qrow] + l_part[6 + qhq][qrow];
        float linv = 1.0f / lt;
        size_t mrow = (size_t)(m0 + qrow) * 256;
#pragma unroll
        for (int vg = 0; vg < 2; vg++) {
            int vcb = w * 32 + vg * 16 + q4 * 4;
            ushort4 pe4 = *(const ushort4*)&pe[mrow + vcb];
            ushort4 z4  = *(const ushort4*)&z[mrow + vcb];
            float r0 = (O[vg][qg][0] * linv + b2f(pe4.x)) * b2f(z4.x);
            float r1 = (O[vg][qg][1] * linv + b2f(pe4.y)) * b2f(z4.y);
            float r2 = (O[vg][qg][2] * linv + b2f(pe4.z)) * b2f(z4.z);
            float r3 = (O[vg][qg][3] * linv + b2f(pe4.w)) * b2f(z4.w);
            uint2 o4;
            o4.x = pk_bf16(r0, r1);
            o4.y = pk_bf16(r2, r3);
            int cn = vcb >> 3;
            int slot = (cn + qrow) & 31;
            *(uint2*)&Us[qrow * 256 + slot * 8 + (vcb & 7)] = o4;
        }
    }

    // ---- fused proj: out_block = Us @ Wproj, 4 quarter-passes ----
    auto stageW = [&](const u16* src, u16* dst) {
#pragma unroll
        for (int j = 0; j < 4; j++) {
            int op = j * 8 + w;                  // 0..31
            int r = op * 2 + lo;                 // local n-row 0..63
            int cn = ((lane & 31) - r) & 31;
            const u16* g = src + (size_t)r * 256 + cn * 8;
            __builtin_amdgcn_global_load_lds(
                (const __attribute__((address_space(1))) unsigned int*)g,
                (__attribute__((address_space(3))) unsigned int*)&dst[op * 512],
                16, 0, 0);
        }
    };

    stageW(WTp, (u16*)Vs2[0]);
    __syncthreads();                   // Us visible + WTp quarter 0 resident

    const int mtl = (w & 3) * 16;      // wave m-tile (local row base)
    const int ntl = (w >> 2) * 32;     // wave n-base within quarter
#pragma unroll
    for (int nq = 0; nq < 4; nq++) {
        if (nq < 3) stageW(WTp + (size_t)(nq + 1) * 64 * 256, (u16*)Vs2[(nq + 1) & 1]);
        const u16* Wl = (const u16*)Vs2[nq & 1];
        f4 a0 = (f4){0.f, 0.f, 0.f, 0.f};
        f4 a1 = (f4){0.f, 0.f, 0.f, 0.f};
        const int mrowL = mtl + l15;
        const int ln0 = ntl + l15, ln1 = ntl + 16 + l15;
        __builtin_amdgcn_s_setprio(1);
#pragma unroll
        for (int c = 0; c < 8; c++) {
            int cc = c * 4 + q4;
            bf8 af = *(const bf8*)&Us[mrowL * 256 + (((cc + mrowL) & 31) << 3)];
            bf8 b0 = *(const bf8*)&Wl[ln0 * 256 + (((cc + ln0) & 31) << 3)];
            bf8 b1 = *(const bf8*)&Wl[ln1 * 256 + (((cc + ln1) & 31) << 3)];
            a0 = __builtin_amdgcn_mfma_f32_16x16x32_bf16(b0, af, a0, 0, 0, 0);
            a1 = __builtin_amdgcn_mfma_f32_16x16x32_bf16(b1, af, a1, 0, 0, 0);
        }
        __builtin_amdgcn_s_setprio(0);
        float* ob = &out[(size_t)(m0 + mrowL) * 256 + nq * 64 + ntl];
        *(f4*)&ob[q4 * 4] = a0;
        *(f4*)&ob[16 + q4 * 4] = a1;
        __syncthreads();               // Wl reads done before its restage;
                                       // next quarter's DMA drained
    }
}

// ---------------------------------------------------------------------------
extern "C" void kernel_launch(void* const* d_in, const int* in_sizes, int n_in,
                              void* d_out, int out_size, void* d_ws, size_t ws_size,
                              hipStream_t stream) {
    (void)in_sizes; (void)n_in; (void)out_size; (void)ws_size;
    const float* x      = (const float*)d_in[0];
    const float* Wqkv   = (const float*)d_in[1];
    const float* Wgate  = (const float*)d_in[2];
    const float* bgate  = (const float*)d_in[3];
    const float* Wproj  = (const float*)d_in[4];
    const float* pw     = (const float*)d_in[5];
    const float* pb     = (const float*)d_in[6];
    float* out = (float*)d_out;

    char* ws = (char*)d_ws;
    u16* WT_all = (u16*)(ws);                   // 524288 B
    u16* WTp    = (u16*)(ws + 524288);          // 131072 B
    u16* q      = (u16*)(ws + 655360);          // 8388608
    u16* k      = (u16*)(ws + 9043968);         // 8388608
    u16* vT     = (u16*)(ws + 17432576);        // 8388608
    u16* z      = (u16*)(ws + 25821184);        // 8388608
    u16* pe     = (u16*)(ws + 34209792);        // 8388608
    u16* xb     = (u16*)(ws + 42598400);        // 8388608 (x as bf16)

    prep_all<<<4176, 256, 0, stream>>>(Wqkv, Wgate, Wproj, x, WT_all, WTp, xb);
    gemm_qkvz<<<dim3(128, 2), 512, 0, stream>>>(xb, WT_all, bgate, q, k, vT, z);
    conv_pe<<<1024, 256, 0, stream>>>(q, pw, pb, pe);
    attn<<<256, 512, 0, stream>>>(q, k, vT, pe, z, WTp, out);
}

// Round 17
// 217.902 us; speedup vs baseline: 1.0341x; 1.0140x over previous
//
#include <hip/hip_runtime.h>
#include <hip/hip_bf16.h>
#include <math.h>
#include <stdint.h>

typedef unsigned short u16;
typedef __attribute__((ext_vector_type(8))) short bf8;    // 8 bf16 raw bits (4 VGPRs)
typedef __attribute__((ext_vector_type(4))) float f4;     // 16x16 MFMA C/D frag

#define SC_LOG2E 0.09016844f   // 256^-0.5 * log2(e)

__device__ __forceinline__ float b2f(u16 u) {
    union { uint32_t i; float f; } v; v.i = ((uint32_t)u) << 16; return v.f;
}
__device__ __forceinline__ u16 f2b(float f) {
    union { float f; uint32_t i; } v; v.f = f;
    uint32_t r = (v.i + 0x7FFFu + ((v.i >> 16) & 1u)) >> 16;
    return (u16)r;
}
// pack two f32 -> two bf16 in one dword (RNE), 1 VALU op
__device__ __forceinline__ uint32_t pk_bf16(float lo, float hi) {
    uint32_t r;
    asm("v_cvt_pk_bf16_f32 %0, %1, %2" : "=v"(r) : "v"(lo), "v"(hi));
    return r;
}

// ---------------------------------------------------------------------------
// Kernel 0: weight prep (transpose via LDS tile, coalesced both sides) +
// x cast, one launch.
// ---------------------------------------------------------------------------
__global__ __launch_bounds__(256) void prep_all(
        const float* __restrict__ Wqkv, const float* __restrict__ Wgate,
        const float* __restrict__ Wproj, const float* __restrict__ x,
        u16* __restrict__ WT_all, u16* __restrict__ WTp,
        u16* __restrict__ xb) {
    int bid = blockIdx.x;
    if (bid < 80) {
        __shared__ float tile[64][65];
        int t = threadIdx.x;
        int lid = (bid < 64) ? bid : (bid - 64);
        int n0 = (lid >> 2) * 64, k0 = (lid & 3) * 64;
        const float* src; int stride, ncol; u16* dst;
        if (bid < 64) {
            if (n0 < 768) { src = Wqkv; stride = 768; ncol = n0; }
            else          { src = Wgate; stride = 256; ncol = n0 - 768; }
            dst = WT_all;
        } else { src = Wproj; stride = 256; ncol = n0; dst = WTp; }
        int cr = t & 63, rr = t >> 6;
#pragma unroll
        for (int i = 0; i < 16; i++) {
            int r = rr * 16 + i;
            tile[r][cr] = src[(size_t)(k0 + r) * stride + ncol + cr];
        }
        __syncthreads();
#pragma unroll
        for (int i = 0; i < 16; i++) {
            int rw = rr * 16 + i;
            dst[(size_t)(n0 + rw) * 256 + k0 + cr] = f2b(tile[cr][rw]);
        }
    } else {
        int i = ((bid - 80) * 256 + threadIdx.x) * 4;
        float4 f = *(const float4*)&x[i];
        uint2 o;
        o.x = pk_bf16(f.x, f.y);
        o.y = pk_bf16(f.z, f.w);
        *(uint2*)&xb[i] = o;
    }
}

// ---------------------------------------------------------------------------
// Kernel 1: fused GEMM  y = xb @ [W_qkv | W_gate]  (v17 persistent-A form).
// v21: ALL panels use swapped mfma(bf, af) -> lane axis = m for every
// output. vT store fixed: was unswapped (lane = vc -> 8KB-strided uint2
// scatter, 16 lines/inst); now 4 scalar u16 stores per acc with 16
// consecutive lanes writing 16 consecutive nn (32B contiguous per row).
// ---------------------------------------------------------------------------
__global__ __launch_bounds__(512) void gemm_qkvz(
        const u16* __restrict__ xb, const u16* __restrict__ WT,
        const float* __restrict__ b_gate,
        u16* __restrict__ qo, u16* __restrict__ ko,
        u16* __restrict__ vT, u16* __restrict__ zo) {
    __shared__ u16 As[64 * 520];       // 128 rows x 256 k, pair-1040B, swz
    __shared__ u16 Bp[2][32 * 520];    // 2 x (64 rows x 256 k)
    const int t = threadIdx.x;
    const int w = t >> 6, lane = t & 63, l15 = lane & 15, q4 = lane >> 4;
    const int m0 = blockIdx.x * 128;
    const int nb = blockIdx.y * 512;   // n-half base within WT (1024 rows)

    const int lo = lane >> 5;
    const int lcn = ((lane & 31) - 4 * lo) & 31;

    auto stageA = [&]() {
#pragma unroll
        for (int rr = 0; rr < 8; rr++) {
            int pp = rr * 8 + w;                 // pair 0..63
            const u16* g = &xb[(size_t)(m0 + pp * 2 + lo) * 256 + lcn * 8];
            __builtin_amdgcn_global_load_lds(
                (const __attribute__((address_space(1))) unsigned int*)g,
                (__attribute__((address_space(3))) unsigned int*)&As[pp * 520],
                16, 0, 0);
        }
    };
    auto stageB = [&](int p, u16* dst) {
#pragma unroll
        for (int rr = 0; rr < 4; rr++) {
            int pp = rr * 8 + w;                 // pair 0..31
            const u16* g = &WT[(size_t)(nb + p * 64 + pp * 2 + lo) * 256 + lcn * 8];
            __builtin_amdgcn_global_load_lds(
                (const __attribute__((address_space(1))) unsigned int*)g,
                (__attribute__((address_space(3))) unsigned int*)&dst[pp * 520],
                16, 0, 0);
        }
    };
    auto kaddr = [&](const u16* base, int row, int cn) -> const u16* {
        int o = row & 1;
        return base + (row >> 1) * 520 + o * 256 + (((cn + 4 * o) & 31) << 3);
    };

    stageA();
    stageB(0, Bp[0]);

    const int mtb = (w & 3) * 32;      // wave m-base (2 m-tiles of 16)
    const int ntb = (w >> 2) * 32;     // wave n-base (2 n-tiles of 16)

    for (int p = 0; p < 8; ++p) {
        __syncthreads();               // A + B[p] DMA drained; B[p+1&1] reads retired
        if (p < 7) stageB(p + 1, Bp[(p + 1) & 1]);
        const u16* Bs = Bp[p & 1];
        const int n0g = nb + p * 64;
        const int kind = n0g >> 8;     // 0=q 1=k 2=vT 3=z
        const int pcol = n0g & 255;

        f4 acc[2][2];
#pragma unroll
        for (int i = 0; i < 2; i++)
#pragma unroll
            for (int j = 0; j < 2; j++) acc[i][j] = (f4){0.f, 0.f, 0.f, 0.f};

        __builtin_amdgcn_s_setprio(1);
#pragma unroll
        for (int c = 0; c < 8; c++) {
            bf8 af0 = *(const bf8*)kaddr(As, mtb + l15, c * 4 + q4);
            bf8 af1 = *(const bf8*)kaddr(As, mtb + 16 + l15, c * 4 + q4);
            bf8 bf0 = *(const bf8*)kaddr(Bs, ntb + l15, c * 4 + q4);
            bf8 bf1 = *(const bf8*)kaddr(Bs, ntb + 16 + l15, c * 4 + q4);
            // swapped for ALL kinds: D[n][m], lane axis = m
            acc[0][0] = __builtin_amdgcn_mfma_f32_16x16x32_bf16(bf0, af0, acc[0][0], 0, 0, 0);
            acc[0][1] = __builtin_amdgcn_mfma_f32_16x16x32_bf16(bf1, af0, acc[0][1], 0, 0, 0);
            acc[1][0] = __builtin_amdgcn_mfma_f32_16x16x32_bf16(bf0, af1, acc[1][0], 0, 0, 0);
            acc[1][1] = __builtin_amdgcn_mfma_f32_16x16x32_bf16(bf1, af1, acc[1][1], 0, 0, 0);
        }
        __builtin_amdgcn_s_setprio(0);

        // acc[i][j][r] = D[n = ntb + j*16 + q4*4 + r][m = mtb + i*16 + l15]
        if (kind == 2) {               // vT[b][vc][nn]: lanes -> consecutive nn
            int bb = m0 >> 12;
            int nnb = (m0 & 4095) + mtb + l15;
#pragma unroll
            for (int i = 0; i < 2; i++) {
                int nn = nnb + i * 16;
#pragma unroll
                for (int j = 0; j < 2; j++) {
                    int vcb = pcol + ntb + j * 16 + q4 * 4;
#pragma unroll
                    for (int r = 0; r < 4; r++)
                        vT[(size_t)(bb * 256 + vcb + r) * 4096 + nn] =
                            f2b(acc[i][j][r]);
                }
            }
        } else if (kind == 3) {        // z = gelu(y + bg)
#pragma unroll
            for (int i = 0; i < 2; i++) {
                size_t mrow = (size_t)(m0 + mtb + i * 16 + l15) * 256 + pcol;
#pragma unroll
                for (int j = 0; j < 2; j++) {
                    int col = ntb + j * 16 + q4 * 4;
                    float4 bg4 = *(const float4*)&b_gate[pcol + col];
                    float v0 = acc[i][j][0] + bg4.x;
                    float v1 = acc[i][j][1] + bg4.y;
                    float v2 = acc[i][j][2] + bg4.z;
                    float v3 = acc[i][j][3] + bg4.w;
                    v0 = 0.5f * v0 * (1.0f + erff(v0 * 0.70710678118654752f));
                    v1 = 0.5f * v1 * (1.0f + erff(v1 * 0.70710678118654752f));
                    v2 = 0.5f * v2 * (1.0f + erff(v2 * 0.70710678118654752f));
                    v3 = 0.5f * v3 * (1.0f + erff(v3 * 0.70710678118654752f));
                    uint2 o;
                    o.x = pk_bf16(v0, v1);
                    o.y = pk_bf16(v2, v3);
                    *(uint2*)&zo[mrow + col] = o;
                }
            }
        } else {                       // q/k
            u16* dst = (kind == 0) ? qo : ko;
#pragma unroll
            for (int i = 0; i < 2; i++) {
                size_t mrow = (size_t)(m0 + mtb + i * 16 + l15) * 256 + pcol;
#pragma unroll
                for (int j = 0; j < 2; j++) {
                    int col = ntb + j * 16 + q4 * 4;
                    uint2 o;
                    o.x = pk_bf16(acc[i][j][0], acc[i][j][1]);
                    o.y = pk_bf16(acc[i][j][2], acc[i][j][3]);
                    *(uint2*)&dst[mrow + col] = o;
                }
            }
        }
    }
}

// ---------------------------------------------------------------------------
// Kernel 2: depthwise 3x3 conv PE, vectorized (4 ch/thread, ushort4 I/O).
// ---------------------------------------------------------------------------
__global__ __launch_bounds__(256) void conv_pe(
        const u16* __restrict__ q, const float* __restrict__ pw,
        const float* __restrict__ pb, u16* __restrict__ pe) {
    const int bid = blockIdx.x;
    const int b = bid >> 8, h = (bid >> 2) & 63, wsg = bid & 3;
    const int t = threadIdx.x;
    const int c4 = (t & 63) * 4;       // channel group (lane -> coalesced)
    const int ws4 = t >> 6;            // wave id -> w-subsegment
    const int w0 = wsg * 16 + ws4 * 4; // first of 4 output w-positions

    float wf[36];
#pragma unroll
    for (int j = 0; j < 9; j++) {
        float4 v = *(const float4*)&pw[c4 * 9 + j * 4];
        wf[j * 4 + 0] = v.x; wf[j * 4 + 1] = v.y;
        wf[j * 4 + 2] = v.z; wf[j * 4 + 3] = v.w;
    }
    float4 bias4 = *(const float4*)&pb[c4];
    float bias[4] = {bias4.x, bias4.y, bias4.z, bias4.w};

    const u16* qb = q + b * (4096 * 256);
    u16* peb = pe + b * (4096 * 256);
    const bool vTop = h > 0, vBot = h < 63;

    float v[3][6][4];
#pragma unroll
    for (int j = 0; j < 6; j++) {
        int pos = w0 - 1 + j;
        bool inw = (pos >= 0) && (pos < 64);
#pragma unroll
        for (int r = 0; r < 3; r++) {
            bool ok = inw && ((r == 0) ? vTop : (r == 2) ? vBot : true);
            ushort4 u4 = {0, 0, 0, 0};
            if (ok) u4 = *(const ushort4*)&qb[((h - 1 + r) * 64 + pos) * 256 + c4];
            v[r][j][0] = b2f(u4.x); v[r][j][1] = b2f(u4.y);
            v[r][j][2] = b2f(u4.z); v[r][j][3] = b2f(u4.w);
        }
    }
#pragma unroll
    for (int w2 = 0; w2 < 4; w2++) {
        float o[4];
#pragma unroll
        for (int ch = 0; ch < 4; ch++) {
            float acc = bias[ch];
#pragma unroll
            for (int r = 0; r < 3; r++)
#pragma unroll
                for (int j = 0; j < 3; j++)
                    acc += wf[ch * 9 + r * 3 + j] * v[r][w2 + j][ch];
            o[ch] = acc;
        }
        uint2 st;
        st.x = pk_bf16(o[0], o[1]);
        st.y = pk_bf16(o[2], o[3]);
        *(uint2*)&peb[(h * 64 + w0 + w2) * 256 + c4] = st;
    }
}

// ---------------------------------------------------------------------------
// Kernel 3: flash attention v19 (measured best) — UNCHANGED.
// ---------------------------------------------------------------------------
__global__ __launch_bounds__(512) void attn(
        const u16* __restrict__ q, const u16* __restrict__ k,
        const u16* __restrict__ vT, const u16* __restrict__ pe,
        const u16* __restrict__ z, const u16* __restrict__ WTp,
        float* __restrict__ out) {
    __shared__ u16 Kst[32 * 520];      // 64 rows x 256, pair-1040B, swizzled
    __shared__ u16 Vs2[2][256 * 64];   // [vc][64 keys], 128B rows, rotated
    __shared__ u16 Ps[64 * 72];        // [q][64 keys + 8 pad]
    __shared__ float l_part[8][64];

    const int t = threadIdx.x;
    const int w = t >> 6, lane = t & 63, l15 = lane & 15, q4 = lane >> 4;
    const int kg = w >> 1, qh = w & 1;
    const int xcd = blockIdx.x & 7;
    const int b = xcd >> 1;
    const int qt = (blockIdx.x >> 3) * 2 + (xcd & 1);
    const int m0 = b * 4096 + qt * 64;

    const u16* kb = k + (size_t)b * 4096 * 256;
    const u16* vbase = vT + (size_t)b * 256 * 4096;

    const int lo = lane >> 5;
    const int lcn = ((lane & 31) - 4 * lo) & 31;

    auto stage64 = [&](const u16* src) {
#pragma unroll
        for (int rr = 0; rr < 4; rr++) {
            int pp = rr * 8 + w;                 // pair index 0..31
            const u16* g = src + (size_t)(pp * 2 + lo) * 256 + lcn * 8;
            u16* l = &Kst[pp * 520];
            __builtin_amdgcn_global_load_lds(
                (const __attribute__((address_space(1))) unsigned int*)g,
                (__attribute__((address_space(3))) unsigned int*)l, 16, 0, 0);
        }
    };
    const int vrl = lane >> 3, vsl = lane & 7;
    auto stageV = [&](const u16* src, u16* dst) {  // src = vbase + kt*64
#pragma unroll
        for (int j = 0; j < 4; j++) {
            int op = j * 8 + w;                  // 0..31
            int r = op * 8 + vrl;
            int cn = (vsl - r) & 7;
            const u16* g = src + (size_t)r * 4096 + cn * 8;
            u16* l = dst + op * 512;
            __builtin_amdgcn_global_load_lds(
                (const __attribute__((address_space(1))) unsigned int*)g,
                (__attribute__((address_space(3))) unsigned int*)l, 16, 0, 0);
        }
    };
    auto kaddr = [&](int row, int cn) -> const u16* {
        int o = row & 1;
        return &Kst[(row >> 1) * 520 + o * 256 + (((cn + 4 * o) & 31) << 3)];
    };

    stage64(q + (size_t)m0 * 256);
    __syncthreads();
    bf8 qf[2][8];
#pragma unroll
    for (int qtt = 0; qtt < 2; qtt++)
#pragma unroll
        for (int c = 0; c < 8; c++)
            qf[qtt][c] = *(const bf8*)kaddr(qh * 32 + qtt * 16 + l15, c * 4 + q4);
    __syncthreads();                   // all qf reads done before K overwrites

    stage64(kb);                       // K[0]
    stageV(vbase, Vs2[0]);             // V[0]

    f4 O[2][4];
#pragma unroll
    for (int vg = 0; vg < 2; vg++)
#pragma unroll
        for (int qg = 0; qg < 4; qg++) O[vg][qg] = (f4){0.f, 0.f, 0.f, 0.f};
    float lrow[2] = {0.f, 0.f};

    auto body = [&](int kt, const u16* Vcur, u16* Vnxt) {
        __syncthreads();               // K[kt] in Kst, V[kt] in Vcur

        f4 St[2];
        St[0] = (f4){0.f, 0.f, 0.f, 0.f};
        St[1] = (f4){0.f, 0.f, 0.f, 0.f};
        __builtin_amdgcn_s_setprio(1);
#pragma unroll
        for (int c = 0; c < 8; c++) {
            bf8 kf = *(const bf8*)kaddr(kg * 16 + l15, c * 4 + q4);
            St[0] = __builtin_amdgcn_mfma_f32_16x16x32_bf16(kf, qf[0][c], St[0], 0, 0, 0);
            St[1] = __builtin_amdgcn_mfma_f32_16x16x32_bf16(kf, qf[1][c], St[1], 0, 0, 0);
        }
        __builtin_amdgcn_s_setprio(0);

#pragma unroll
        for (int qtt = 0; qtt < 2; qtt++) {
            float e0 = exp2f(St[qtt][0] * SC_LOG2E);
            float e1 = exp2f(St[qtt][1] * SC_LOG2E);
            float e2 = exp2f(St[qtt][2] * SC_LOG2E);
            float e3 = exp2f(St[qtt][3] * SC_LOG2E);
            uint2 pk;
            pk.x = pk_bf16(e0, e1);
            pk.y = pk_bf16(e2, e3);
            int qrow = qh * 32 + qtt * 16 + l15;
            *(uint2*)&Ps[qrow * 72 + kg * 16 + q4 * 4] = pk;
            lrow[qtt] += (e0 + e1) + (e2 + e3);   // per-lane partial; reduce after loop
        }
        __syncthreads();               // P visible; Kst kf reads done

        if (kt < 63) {
            stage64(kb + (size_t)(kt + 1) * 16384);
            stageV(vbase + (size_t)(kt + 1) * 64, Vnxt);
        }

        bf8 pf[4][2], vfr[2][2];
#pragma unroll
        for (int qg = 0; qg < 4; qg++)
#pragma unroll
            for (int kh = 0; kh < 2; kh++)
                pf[qg][kh] = *(bf8*)&Ps[(qg * 16 + l15) * 72 + kh * 32 + q4 * 8];
#pragma unroll
        for (int vg = 0; vg < 2; vg++)
#pragma unroll
            for (int kh = 0; kh < 2; kh++) {
                int R = w * 32 + vg * 16 + l15;
                int slot = ((kh * 4 + q4) + R) & 7;
                vfr[vg][kh] = *(const bf8*)&Vcur[R * 64 + slot * 8];
            }
        __builtin_amdgcn_s_setprio(1);
#pragma unroll
        for (int vg = 0; vg < 2; vg++)
#pragma unroll
            for (int qg = 0; qg < 4; qg++) {
                O[vg][qg] = __builtin_amdgcn_mfma_f32_16x16x32_bf16(
                    vfr[vg][0], pf[qg][0], O[vg][qg], 0, 0, 0);
                O[vg][qg] = __builtin_amdgcn_mfma_f32_16x16x32_bf16(
                    vfr[vg][1], pf[qg][1], O[vg][qg], 0, 0, 0);
            }
        __builtin_amdgcn_s_setprio(0);
    };

    for (int kt2 = 0; kt2 < 64; kt2 += 2) {
        body(kt2,     Vs2[0], Vs2[1]);
        body(kt2 + 1, Vs2[1], Vs2[0]);
    }

    // ---- deferred l-reduction: once instead of per-iter ----
#pragma unroll
    for (int qtt = 0; qtt < 2; qtt++) {
        float s = lrow[qtt];
        s += __shfl_xor(s, 16);
        s += __shfl_xor(s, 32);
        lrow[qtt] = s;
    }
    if (q4 == 0) {
        l_part[w][qh * 32 + l15] = lrow[0];
        l_part[w][qh * 32 + 16 + l15] = lrow[1];
    }
    __syncthreads();                   // loop LDS traffic fully retired

    // ---- epilogue: u = (O/l + pe) * z -> bf16 into Us (Kst space) ----
    u16* Us = Kst;
#pragma unroll
    for (int qg = 0; qg < 4; qg++) {
        int qrow = qg * 16 + l15;
        int qhq = qg >> 1;
        float lt = l_part[qhq][qrow] + l_part[2 + qhq][qrow]
                 + l_part[4 + qhq][qrow] + l_part[6 + qhq][qrow];
        float linv = 1.0f / lt;
        size_t mrow = (size_t)(m0 + qrow) * 256;
#pragma unroll
        for (int vg = 0; vg < 2; vg++) {
            int vcb = w * 32 + vg * 16 + q4 * 4;
            ushort4 pe4 = *(const ushort4*)&pe[mrow + vcb];
            ushort4 z4  = *(const ushort4*)&z[mrow + vcb];
            float r0 = (O[vg][qg][0] * linv + b2f(pe4.x)) * b2f(z4.x);
            float r1 = (O[vg][qg][1] * linv + b2f(pe4.y)) * b2f(z4.y);
            float r2 = (O[vg][qg][2] * linv + b2f(pe4.z)) * b2f(z4.z);
            float r3 = (O[vg][qg][3] * linv + b2f(pe4.w)) * b2f(z4.w);
            uint2 o4;
            o4.x = pk_bf16(r0, r1);
            o4.y = pk_bf16(r2, r3);
            int cn = vcb >> 3;
            int slot = (cn + qrow) & 31;
            *(uint2*)&Us[qrow * 256 + slot * 8 + (vcb & 7)] = o4;
        }
    }

    // ---- fused proj: out_block = Us @ Wproj, 4 quarter-passes ----
    auto stageW = [&](const u16* src, u16* dst) {
#pragma unroll
        for (int j = 0; j < 4; j++) {
            int op = j * 8 + w;                  // 0..31
            int r = op * 2 + lo;                 // local n-row 0..63
            int cn = ((lane & 31) - r) & 31;
            const u16* g = src + (size_t)r * 256 + cn * 8;
            __builtin_amdgcn_global_load_lds(
                (const __attribute__((address_space(1))) unsigned int*)g,
                (__attribute__((address_space(3))) unsigned int*)&dst[op * 512],
                16, 0, 0);
        }
    };

    stageW(WTp, (u16*)Vs2[0]);
    __syncthreads();                   // Us visible + WTp quarter 0 resident

    const int mtl = (w & 3) * 16;      // wave m-tile (local row base)
    const int ntl = (w >> 2) * 32;     // wave n-base within quarter
#pragma unroll
    for (int nq = 0; nq < 4; nq++) {
        if (nq < 3) stageW(WTp + (size_t)(nq + 1) * 64 * 256, (u16*)Vs2[(nq + 1) & 1]);
        const u16* Wl = (const u16*)Vs2[nq & 1];
        f4 a0 = (f4){0.f, 0.f, 0.f, 0.f};
        f4 a1 = (f4){0.f, 0.f, 0.f, 0.f};
        const int mrowL = mtl + l15;
        const int ln0 = ntl + l15, ln1 = ntl + 16 + l15;
        __builtin_amdgcn_s_setprio(1);
#pragma unroll
        for (int c = 0; c < 8; c++) {
            int cc = c * 4 + q4;
            bf8 af = *(const bf8*)&Us[mrowL * 256 + (((cc + mrowL) & 31) << 3)];
            bf8 b0 = *(const bf8*)&Wl[ln0 * 256 + (((cc + ln0) & 31) << 3)];
            bf8 b1 = *(const bf8*)&Wl[ln1 * 256 + (((cc + ln1) & 31) << 3)];
            a0 = __builtin_amdgcn_mfma_f32_16x16x32_bf16(b0, af, a0, 0, 0, 0);
            a1 = __builtin_amdgcn_mfma_f32_16x16x32_bf16(b1, af, a1, 0, 0, 0);
        }
        __builtin_amdgcn_s_setprio(0);
        float* ob = &out[(size_t)(m0 + mrowL) * 256 + nq * 64 + ntl];
        *(f4*)&ob[q4 * 4] = a0;
        *(f4*)&ob[16 + q4 * 4] = a1;
        __syncthreads();               // Wl reads done before its restage;
                                       // next quarter's DMA drained
    }
}

// ---------------------------------------------------------------------------
extern "C" void kernel_launch(void* const* d_in, const int* in_sizes, int n_in,
                              void* d_out, int out_size, void* d_ws, size_t ws_size,
                              hipStream_t stream) {
    (void)in_sizes; (void)n_in; (void)out_size; (void)ws_size;
    const float* x      = (const float*)d_in[0];
    const float* Wqkv   = (const float*)d_in[1];
    const float* Wgate  = (const float*)d_in[2];
    const float* bgate  = (const float*)d_in[3];
    const float* Wproj  = (const float*)d_in[4];
    const float* pw     = (const float*)d_in[5];
    const float* pb     = (const float*)d_in[6];
    float* out = (float*)d_out;

    char* ws = (char*)d_ws;
    u16* WT_all = (u16*)(ws);                   // 524288 B
    u16* WTp    = (u16*)(ws + 524288);          // 131072 B
    u16* q      = (u16*)(ws + 655360);          // 8388608
    u16* k      = (u16*)(ws + 9043968);         // 8388608
    u16* vT     = (u16*)(ws + 17432576);        // 8388608
    u16* z      = (u16*)(ws + 25821184);        // 8388608
    u16* pe     = (u16*)(ws + 34209792);        // 8388608
    u16* xb     = (u16*)(ws + 42598400);        // 8388608 (x as bf16)

    prep_all<<<4176, 256, 0, stream>>>(Wqkv, Wgate, Wproj, x, WT_all, WTp, xb);
    gemm_qkvz<<<dim3(128, 2), 512, 0, stream>>>(xb, WT_all, bgate, q, k, vT, z);
    conv_pe<<<1024, 256, 0, stream>>>(q, pw, pb, pe);
    attn<<<256, 512, 0, stream>>>(q, k, vT, pe, z, WTp, out);
}